// Round 12
// baseline (21.882 us; speedup 1.0000x reference)
//
#include <hip/hip_runtime.h>
#include <hip/hip_bf16.h>
#include <math.h>

#define BS 128
#define NQ 300
#define NT 16
#define CPL 5   // columns per lane: 300 = 60 lanes * 5 cols, lanes 60..63 idle

union DI { double d; int i[2]; };

// f64 value-only min reduce step via DPP (VALU latency, no index carry).
// bestv is never NaN here (NaN excluded at the per-lane tree).
#define DPP_MIN_STEP(CTRL)                                                    \
    {                                                                         \
        DI a_; a_.d = bestv;                                                  \
        DI p_;                                                                \
        p_.i[0] = __builtin_amdgcn_update_dpp(a_.i[0], a_.i[0], CTRL, 0xF, 0xF, false); \
        p_.i[1] = __builtin_amdgcn_update_dpp(a_.i[1], a_.i[1], CTRL, 0xF, 0xF, false); \
        bestv = fmin(bestv, p_.d);                                            \
    }
#define DPP_MIN_ALL  DPP_MIN_STEP(0x111) DPP_MIN_STEP(0x112) DPP_MIN_STEP(0x114) \
                     DPP_MIN_STEP(0x118) DPP_MIN_STEP(0x142) DPP_MIN_STEP(0x143)

__device__ __forceinline__ double readlane_d(double x, int lane) {
    DI a; a.d = x;
    DI r;
    r.i[0] = __builtin_amdgcn_readlane(a.i[0], lane);
    r.i[1] = __builtin_amdgcn_readlane(a.i[1], lane);
    return r.d;
}

__device__ __forceinline__ int sel5(const int* a, int slot) {
    int r = a[0];
    r = (slot == 1) ? a[1] : r;
    r = (slot == 2) ? a[2] : r;
    r = (slot == 3) ? a[3] : r;
    r = (slot == 4) ? a[4] : r;
    return r;
}

// ---------------------------------------------------------------------------
// One 256-thread block (4 waves) per batch:
//   waves 0-3: cost compute (bit-identical f32 expression) -> C (f32) and
//              LDS tile as f64 (exact cast, once).
//   wave 0:    R6-proven greedy rowmin init + exact f64 Dijkstra fallback,
//              barrier-free (R10-proven). Popped-column exclusion via
//              cand[]=NaN (r < NaN == false freezes minv/path exactly like
//              numpy's `remaining`); per-lane tree uses a finite sentinel.
// Trajectory (pop sequence, tie-breaks, f64 eval order) identical to R11.
// ---------------------------------------------------------------------------
__global__ __launch_bounds__(256) void lsa_fused(const float* __restrict__ pred_boxes, // [BS,NQ,4]
                                                 const float* __restrict__ logits_b,   // [BS,NQ,2]
                                                 const float* __restrict__ tgt_boxes,  // [BS,NT,5]
                                                 float* __restrict__ C,                // [BS,NQ,NT]
                                                 float* __restrict__ rows_out,         // [BS,NT]
                                                 float* __restrict__ cols_out)         // [BS,NT]
{
    const int b   = blockIdx.x;
    const int tid = threadIdx.x;

    __shared__ double costd[NT][NQ];         // f64 tile: 38.4 KB
    __shared__ double u_add[NT];
    __shared__ __align__(16) float tgt_s[NT][4];

    if (tid < 64) {
        int t = tid >> 2, d = tid & 3;
        tgt_s[t][d] = tgt_boxes[((size_t)b * NT + t) * 5 + 1 + d];
    }
    if (tid < NT) u_add[tid] = 0.0;
    __syncthreads();

    // ---- parallel cost compute (4 waves) ----
    float* Cb = C + (size_t)b * NQ * NT;
    for (int q = tid; q < NQ; q += 256) {
        float4 pb = *reinterpret_cast<const float4*>(pred_boxes + ((size_t)b * NQ + q) * 4);
        float2 lg = *reinterpret_cast<const float2*>(logits_b  + ((size_t)b * NQ + q) * 2);
        float pcx = pb.x, pcy = pb.y, pw = pb.z, ph = pb.w;
        float mm = fmaxf(lg.x, lg.y);
        float e0 = expf(lg.x - mm), e1 = expf(lg.y - mm);
        float p1 = e1 / (e0 + e1);
        float ax1 = pcx - 0.5f * pw, ay1 = pcy - 0.5f * ph;
        float ax2 = pcx + 0.5f * pw, ay2 = pcy + 0.5f * ph;
        float area_a = (ax2 - ax1) * (ay2 - ay1);

        float cv[NT];
        #pragma unroll
        for (int t = 0; t < NT; ++t) {
            float tcx = tgt_s[t][0], tcy = tgt_s[t][1], tw = tgt_s[t][2], th = tgt_s[t][3];
            float cost_bbox = fabsf(pcx - tcx) + fabsf(pcy - tcy) + fabsf(pw - tw) + fabsf(ph - th);
            float bx1 = tcx - 0.5f * tw, by1 = tcy - 0.5f * th;
            float bx2 = tcx + 0.5f * tw, by2 = tcy + 0.5f * th;
            float area_b = (bx2 - bx1) * (by2 - by1);
            float ltx = fmaxf(ax1, bx1), lty = fmaxf(ay1, by1);
            float rbx = fminf(ax2, bx2), rby = fminf(ay2, by2);
            float wx = fmaxf(rbx - ltx, 0.0f), wy = fmaxf(rby - lty, 0.0f);
            float inter = wx * wy;
            float uni = area_a + area_b - inter;
            float iou = inter / uni;
            float ex1 = fminf(ax1, bx1), ey1 = fminf(ay1, by1);
            float ex2 = fmaxf(ax2, bx2), ey2 = fmaxf(ay2, by2);
            float ewx = fmaxf(ex2 - ex1, 0.0f), ewy = fmaxf(ey2 - ey1, 0.0f);
            float area_e = ewx * ewy;
            float giou = iou - (area_e - uni) / area_e;
            float ct = 5.0f * cost_bbox - 2.0f * giou - p1;
            cv[t] = ct;
            costd[t][q] = (double)ct;        // exact cast, once
        }
        float4* dst = reinterpret_cast<float4*>(Cb + (size_t)q * NT);
        dst[0] = make_float4(cv[0],  cv[1],  cv[2],  cv[3]);
        dst[1] = make_float4(cv[4],  cv[5],  cv[6],  cv[7]);
        dst[2] = make_float4(cv[8],  cv[9],  cv[10], cv[11]);
        dst[3] = make_float4(cv[12], cv[13], cv[14], cv[15]);
    }
    __syncthreads();
    if (tid >= 64) return;               // waves 1-3 done; wave 0 continues

    const int  lane       = tid;
    const bool has_cols   = (lane < 60);
    const int  cbase      = has_cols ? lane * CPL : 0;
    const unsigned valid0 = has_cols ? 0x1Fu : 0u;
    const double DNAN     = __builtin_nan("");
    const double SENT     = 1e301;       // > any real minv, < nothing

    double v_reg[CPL];
    int    r4c_reg[CPL];
    int    path_reg[CPL];
    #pragma unroll
    for (int j = 0; j < CPL; ++j) { v_reg[j] = 0.0; r4c_reg[j] = -1; path_reg[j] = -1; }
    double u_reg   = 0.0;     // u[lane] on lanes 0..15
    int    c4r_reg = -1;      // col4row[lane] on lanes 0..15 (-1 elsewhere)

    // ---- rowmin greedy init (f64 reads; argmin identical to f32 version) ----
    int jstar[NT];
    #pragma unroll
    for (int i = 0; i < NT; ++i) {
        const double* crow = &costd[0][0] + i * NQ + cbase;
        double bv = SENT; int bj = 0;
        #pragma unroll
        for (int j = 0; j < CPL; ++j) {
            double c = has_cols ? crow[j] : SENT;
            if (c < bv) { bv = c; bj = j; }          // ascending j => first-min
        }
        double bestv = bv;
        DPP_MIN_ALL
        double m = readlane_d(bestv, 63);
        unsigned long long tied = __ballot(bv == m);
        int l = __ffsll(tied) - 1;                   // smallest lane = smallest col block
        jstar[i] = __builtin_amdgcn_readlane(cbase + bj, l);
        if (lane == i) u_reg = m;                    // == (double)f32_rowmin exactly
    }

    unsigned unassigned = 0;
    #pragma unroll
    for (int i = 0; i < NT; ++i) {
        int k = jstar[i];
        unsigned long long mmk = __ballot(c4r_reg == k);   // row4col[k] inverse lookup
        int rk = mmk ? (__ffsll(mmk) - 1) : -1;
        if (rk == -1) {
            int owner = k / CPL;
            int slot  = k - owner * CPL;
            bool me = (lane == owner);
            r4c_reg[0] = (me && slot == 0) ? i : r4c_reg[0];
            r4c_reg[1] = (me && slot == 1) ? i : r4c_reg[1];
            r4c_reg[2] = (me && slot == 2) ? i : r4c_reg[2];
            r4c_reg[3] = (me && slot == 3) ? i : r4c_reg[3];
            r4c_reg[4] = (me && slot == 4) ? i : r4c_reg[4];
            c4r_reg    = (lane == i) ? k : c4r_reg;
        } else {
            unassigned |= (1u << i);
        }
    }

    // ---- exact f64 Dijkstra augmentation for conflicted rows ----
    for (int cur_row = 0; cur_row < NT; ++cur_row) {
        if (!((unassigned >> cur_row) & 1u)) continue;

        // cand: live candidate (NaN = popped/invalid); minv: frozen values
        double cand[CPL], minv_reg[CPL];
        #pragma unroll
        for (int j = 0; j < CPL; ++j) {
            cand[j]     = (valid0 & (1u << j)) ? 1e300 : DNAN;
            minv_reg[j] = 1e300;
            path_reg[j] = -1;
        }

        double shortest = 0.0;
        int i = cur_row;
        int sink = -1;

        for (int guard = 0; guard <= NT && sink < 0; ++guard) {
            const double ui = readlane_d(u_reg, i);

            const double* crow = &costd[0][0] + i * NQ + cbase;
            double cq[CPL];
            #pragma unroll
            for (int j = 0; j < CPL; ++j) cq[j] = crow[j];

            // relax (NaN cand freezes popped cols) + per-lane first-min tree
            double bestv = SENT;
            int    bj    = NQ;           // sentinel: all-excluded guard
            #pragma unroll
            for (int j = 0; j < CPL; ++j) {
                // numpy order: ((shortest + cost) - u) - v
                double r = ((shortest + cq[j]) - ui) - v_reg[j];
                bool upd = r < cand[j];                  // false if cand NaN
                cand[j]     = upd ? r : cand[j];
                minv_reg[j] = upd ? r : minv_reg[j];
                path_reg[j] = upd ? i : path_reg[j];
                double cv = cand[j];
                if (cv < bestv) { bestv = cv; bj = j; } // NaN auto-excluded
            }
            int bestc = (bj >= NQ) ? NQ : (cbase + bj);

            DPP_MIN_ALL

            const double m = readlane_d(bestv, 63);
            unsigned long long tied = __ballot(bestv == m);
            int l = __ffsll(tied) - 1;
            int k = __builtin_amdgcn_readlane(bestc, l);
            if (k >= NQ) break;          // all excluded; never on valid data
            shortest = m;

            int owner = k / CPL;
            int slot  = k - owner * CPL;
            {   // mark popped: cand[slot] = NaN on owner lane (minv frozen)
                bool me = (lane == owner);
                cand[0] = (me && slot == 0) ? DNAN : cand[0];
                cand[1] = (me && slot == 1) ? DNAN : cand[1];
                cand[2] = (me && slot == 2) ? DNAN : cand[2];
                cand[3] = (me && slot == 3) ? DNAN : cand[3];
                cand[4] = (me && slot == 4) ? DNAN : cand[4];
            }

            unsigned long long mmk = __ballot(c4r_reg == k);
            int rk = mmk ? (__ffsll(mmk) - 1) : -1;
            if (rk == -1) sink = k;
            else          i = rk;
        }

        // dual updates: scanned (= popped) columns have cand NaN
        #pragma unroll
        for (int j = 0; j < CPL; ++j) {
            bool scanned = (valid0 & (1u << j)) && (cand[j] != cand[j]);
            if (scanned) {
                double d = shortest - minv_reg[j];
                int r = r4c_reg[j];
                if (r != -1) u_add[r] = d;      // rows distinct, no race
                v_reg[j] -= d;
            }
        }
        if (lane == cur_row) u_reg += shortest;
        if (lane < NT) { u_reg += u_add[lane]; u_add[lane] = 0.0; }

        // augment along path (uniform scalar walk on registers)
        if (sink >= 0) {
            int j = sink;
            #pragma unroll 1
            for (int it = 0; it <= NT; ++it) {
                int ow = j / CPL;
                int sl = j - ow * CPL;
                int ii = __builtin_amdgcn_readlane(sel5(path_reg, sl), ow);
                bool me = (lane == ow);
                r4c_reg[0] = (me && sl == 0) ? ii : r4c_reg[0];
                r4c_reg[1] = (me && sl == 1) ? ii : r4c_reg[1];
                r4c_reg[2] = (me && sl == 2) ? ii : r4c_reg[2];
                r4c_reg[3] = (me && sl == 3) ? ii : r4c_reg[3];
                r4c_reg[4] = (me && sl == 4) ? ii : r4c_reg[4];
                int tmp = __builtin_amdgcn_readlane(c4r_reg, ii);
                c4r_reg = (lane == ii) ? j : c4r_reg;
                j = tmp;
                if (ii == cur_row) break;
            }
        }
    }

    // ---- outputs: order = argsort(col4row) via rank (values distinct) ----
    int myval = c4r_reg;
    int rank = 0;
    #pragma unroll
    for (int s = 0; s < NT; ++s) {
        int vs = __builtin_amdgcn_readlane(c4r_reg, s);
        rank += (vs < myval) ? 1 : 0;
    }
    if (lane < NT) {
        rows_out[b * NT + rank] = (float)myval;
        cols_out[b * NT + rank] = (float)lane;
    }
}

extern "C" void kernel_launch(void* const* d_in, const int* in_sizes, int n_in,
                              void* d_out, int out_size, void* d_ws, size_t ws_size,
                              hipStream_t stream) {
    const float* pred_boxes = (const float*)d_in[1];
    const float* logits_b   = (const float*)d_in[2];
    const float* tgt_boxes  = (const float*)d_in[3];

    float* C    = (float*)d_out;                   // [BS,NQ,NT]
    float* rows = C + (size_t)BS * NQ * NT;        // [BS,NT]
    float* cols = rows + (size_t)BS * NT;          // [BS,NT]

    lsa_fused<<<BS, 256, 0, stream>>>(pred_boxes, logits_b, tgt_boxes, C, rows, cols);
}